// Round 7
// baseline (517.096 us; speedup 1.0000x reference)
//
#include <hip/hip_runtime.h>
#include <hip/hip_bf16.h>
#include <stdint.h>

#define N_NODES   65536
#define N_GRAPHS  1024
#define N_EDGES   1048576
#define IN_FEATS  512
#define HIDDEN    1024
#define H4        256
#define EMB_DIM   512
#define RDIM      1792   // 512 + 1024 + 256
#define EPS_F     1e-5f
#define SLOPE_F   0.01f

typedef __bf16 bf16;
typedef __bf16 bf16x4 __attribute__((ext_vector_type(4)));
typedef __bf16 bf16x8 __attribute__((ext_vector_type(8)));
typedef float  floatx4 __attribute__((ext_vector_type(4)));

#define GLDS16(gp, lp) __builtin_amdgcn_global_load_lds( \
    (const __attribute__((address_space(1))) void*)(gp), \
    (__attribute__((address_space(3))) void*)(lp), 16, 0, 0)

// -------------------------------------------- fused edge pass, per graph
__global__ __launch_bounds__(256) void k_graph_build(
    const int* __restrict__ src, const int* __restrict__ dst,
    const float* __restrict__ ew,
    bf16* __restrict__ adjb, float* __restrict__ scl_o)
{
    __shared__ float sAdj[4096];
    __shared__ float sDegO[64], sDegI[64];
    int g = blockIdx.x, tid = threadIdx.x;
    for (int i = tid; i < 4096; i += 256) sAdj[i] = 0.f;
    if (tid < 64) { sDegO[tid] = 0.f; sDegI[tid] = 0.f; }
    __syncthreads();
    int e0 = g * 1024;
    #pragma unroll
    for (int i = 0; i < 4; ++i) {
        int e = e0 + i * 256 + tid;
        int s = src[e] & 63, d = dst[e] & 63;
        atomicAdd(&sAdj[(d << 6) | s], ew[e]);
        atomicAdd(&sDegO[s], 1.f);
        atomicAdd(&sDegI[d], 1.f);
    }
    __syncthreads();
    if (tid < 64) scl_o[g * 64 + tid] = rsqrtf(fmaxf(sDegO[tid], 1.f));
    bf16* ag = adjb + ((size_t)g << 12);
    for (int i = tid; i < 4096; i += 256) {
        float si = rsqrtf(fmaxf(sDegI[i >> 6], 1.f));
        ag[i] = (bf16)(sAdj[i] * si);
    }
}

// ---------------- tiled transpose W[K][N] -> WT[N][K] bf16 (coalesced r/w)
__global__ __launch_bounds__(256) void k_transpose_t(
    const float* __restrict__ W, bf16* __restrict__ WT, int K, int N)
{
    __shared__ float sT[64][65];            // pitch 65: conflict-free cols
    const int k0 = blockIdx.x * 64, n0 = blockIdx.y * 64;
    const int tid = threadIdx.x;
    const int lr = tid >> 4, lc = (tid & 15) * 4;
    #pragma unroll
    for (int i = 0; i < 4; ++i) {
        int row = lr + i * 16;
        float4 v = *(const float4*)&W[(size_t)(k0 + row) * N + n0 + lc];
        sT[row][lc + 0] = v.x; sT[row][lc + 1] = v.y;
        sT[row][lc + 2] = v.z; sT[row][lc + 3] = v.w;
    }
    __syncthreads();
    const int nn = tid >> 2, kk0 = (tid & 3) * 16;
    #pragma unroll
    for (int h = 0; h < 2; ++h) {
        bf16x8 o;
        #pragma unroll
        for (int j = 0; j < 8; ++j)
            o[j] = (bf16)sT[kk0 + h * 8 + j][nn];
        *(bf16x8*)&WT[(size_t)(n0 + nn) * K + k0 + kk0 + h * 8] = o;
    }
}

// -------------------------------------- fused prep + agg layer 1 (2 blk/graph)
__global__ __launch_bounds__(256) void k_prep_agg1(
    const float* __restrict__ x, const float* __restrict__ so,
    const bf16* __restrict__ adjb,
    bf16* __restrict__ axs1, bf16* __restrict__ Rb)
{
    __shared__ __align__(16) bf16 sXr[64 * 260];   // (x*so) bf16, pitch 260
    __shared__ __align__(16) bf16 sOut[64 * 264];
    __shared__ float sR[4][256];
    __shared__ float sSo[64];
    int g = blockIdx.x >> 1, half = blockIdx.x & 1;
    int tid = threadIdx.x, lane = tid & 63, wave = tid >> 6, q = lane >> 4;
    if (tid < 64) sSo[tid] = so[g * 64 + tid];
    __syncthreads();

    const float* xg = x + (size_t)g * 64 * IN_FEATS + half * 256;
    const bf16* ag = adjb + ((size_t)g << 12);

    bf16x8 af[4][2];
    #pragma unroll
    for (int mt = 0; mt < 4; ++mt)
        #pragma unroll
        for (int kk = 0; kk < 2; ++kk)
            af[mt][kk] = *(const bf16x8*)&ag[(mt * 16 + (lane & 15)) * 64 + kk * 32 + q * 8];

    float r0a = 0.f, r0b = 0.f, r0c = 0.f, r0d = 0.f;
    #pragma unroll
    for (int i = 0; i < 16; ++i) {
        int row = i * 4 + wave;
        float4 v = *(const float4*)&xg[(size_t)row * IN_FEATS + lane * 4];
        r0a += v.x; r0b += v.y; r0c += v.z; r0d += v.w;
        float sc = sSo[row];
        bf16x4 p;
        p[0] = (bf16)(v.x * sc); p[1] = (bf16)(v.y * sc);
        p[2] = (bf16)(v.z * sc); p[3] = (bf16)(v.w * sc);
        *(bf16x4*)&sXr[row * 260 + lane * 4] = p;
    }
    sR[wave][lane * 4 + 0] = r0a;
    sR[wave][lane * 4 + 1] = r0b;
    sR[wave][lane * 4 + 2] = r0c;
    sR[wave][lane * 4 + 3] = r0d;
    __syncthreads();

    {
        float s = sR[0][tid] + sR[1][tid] + sR[2][tid] + sR[3][tid];
        Rb[(size_t)g * RDIM + half * 256 + tid] = (bf16)(s * (1.f / 64.f));
    }

    #pragma unroll
    for (int nt = 0; nt < 4; ++nt) {
        int cl = wave * 64 + nt * 16 + (lane & 15);     // 0..255
        floatx4 acc[4] = {};
        #pragma unroll
        for (int kk = 0; kk < 2; ++kk) {
            bf16x8 bfrag;
            #pragma unroll
            for (int j = 0; j < 8; ++j)
                bfrag[j] = sXr[(kk * 32 + q * 8 + j) * 260 + cl];
            #pragma unroll
            for (int mt = 0; mt < 4; ++mt)
                acc[mt] = __builtin_amdgcn_mfma_f32_16x16x32_bf16(af[mt][kk], bfrag, acc[mt], 0, 0, 0);
        }
        #pragma unroll
        for (int mt = 0; mt < 4; ++mt)
            #pragma unroll
            for (int i = 0; i < 4; ++i)
                sOut[(mt * 16 + q * 4 + i) * 264 + cl] = (bf16)acc[mt][i];
    }
    __syncthreads();
    #pragma unroll
    for (int it = 0; it < 8; ++it) {
        int idx = it * 256 + tid;
        int d = idx >> 5, c8 = idx & 31;
        *(bf16x8*)&axs1[(size_t)(g * 64 + d) * IN_FEATS + half * 256 + c8 * 8] =
            *(const bf16x8*)&sOut[d * 264 + c8 * 8];
    }
}

// ============================ fused GEMM1 + GN1 + GEMM2 + agg + GN2 ==========
// Continuous cross-ct pipeline: global slot s = ct*8+t uses buf s%3; body t
// stages slot s+2 (so ct's t=6,7 prefetch next ct's first tiles). W2 read as
// 16 register fragments direct from L2 at t=6 (no LDS staging, no vmcnt(0)
// drain). GN1->gemm2 barrier is raw s_barrier + lgkmcnt only, keeping staged
// loads in flight. Wait ledger (FIFO vmcnt): t in 1..6: vmcnt(4);
// t=7: vmcnt(20) [ct<7: newer = next0(4)+w2(16)] / vmcnt(16) [ct=7];
// t=0,ct>0: vmcnt(20) [<= true after-count 28].
__global__ __launch_bounds__(512) void k_gemm12(
    const bf16* __restrict__ A, const bf16* __restrict__ BT1,
    const bf16* __restrict__ BT2, const bf16* __restrict__ adjb,
    const float* __restrict__ al1, const float* __restrict__ ga1, const float* __restrict__ be1,
    const float* __restrict__ al2, const float* __restrict__ ga2, const float* __restrict__ be2,
    const float* __restrict__ so, bf16* __restrict__ Rb)
{
    __shared__ __align__(16) bf16 sm[66560];
    __shared__ float sSo[128];
    const int tid = threadIdx.x;
    const int lane = tid & 63, wave = tid >> 6, q = lane >> 4;
    const int wm = wave >> 2, wn = wave & 3;
    const int by = blockIdx.x;
    const int row0 = by * 128;
    const int gw = by * 2 + wm;
    if (tid < 128) sSo[tid] = so[row0 + tid];

    floatx4 acc2[4][4] = {};
    bf16* sX = sm + 49152;

    auto stage_slot = [&](int s) {               // 4 vm-insts per thread
        int k0 = (s & 7) * 64;
        int ctp = s >> 3;
        int buf = s % 3;
        #pragma unroll
        for (int ro = 0; ro < 2; ++ro) {
            int u = ro * 4096 + wave * 512 + lane * 8;
            int r = u >> 6, c = ((u >> 3) & 7) ^ (r & 7);
            GLDS16(A   + (size_t)(row0 + r) * IN_FEATS + k0 + c * 8,
                   sm + buf * 16384 + ro * 4096 + wave * 512);
            GLDS16(BT1 + (size_t)(ctp * 128 + r) * IN_FEATS + k0 + c * 8,
                   sm + buf * 16384 + 8192 + ro * 4096 + wave * 512);
        }
    };

    // prologue: slots 0,1 in flight
    stage_slot(0);
    stage_slot(1);

    #pragma unroll 1
    for (int ct = 0; ct < 8; ++ct) {
        floatx4 acc1[4][2] = {};
        bf16x8 bfr2[4][4];
        const int b0 = (2 * ct) % 3;

        auto mfma_step = [&](int buf) {
            const bf16* sA = sm + buf * 16384;
            const bf16* sB = sA + 8192;
            #pragma unroll
            for (int kk = 0; kk < 2; ++kk) {
                bf16x8 afr[4], bfr[2];
                int cw = kk * 4 + q;
                #pragma unroll
                for (int mt = 0; mt < 4; ++mt) {
                    int r = wm * 64 + mt * 16 + (lane & 15);
                    afr[mt] = *(const bf16x8*)&sA[(r * 8 + (cw ^ (r & 7))) * 8];
                }
                #pragma unroll
                for (int nt = 0; nt < 2; ++nt) {
                    int r = wn * 32 + nt * 16 + (lane & 15);
                    bfr[nt] = *(const bf16x8*)&sB[(r * 8 + (cw ^ (r & 7))) * 8];
                }
                #pragma unroll
                for (int mt = 0; mt < 4; ++mt)
                    #pragma unroll
                    for (int nt = 0; nt < 2; ++nt)
                        acc1[mt][nt] = __builtin_amdgcn_mfma_f32_16x16x32_bf16(
                            afr[mt], bfr[nt], acc1[mt][nt], 0, 0, 0);
            }
        };

        #pragma unroll
        for (int t = 0; t < 8; ++t) {
            if (t == 0) {
                if (ct == 0) { asm volatile("s_waitcnt vmcnt(4)" ::: "memory"); }
                else         { asm volatile("s_waitcnt vmcnt(20)" ::: "memory"); }
            } else if (t == 7) {
                if (ct < 7)  { asm volatile("s_waitcnt vmcnt(20)" ::: "memory"); }
                else         { asm volatile("s_waitcnt vmcnt(16)" ::: "memory"); }
            } else {
                asm volatile("s_waitcnt vmcnt(4)" ::: "memory");
            }
            __builtin_amdgcn_s_barrier();
            int s2 = ct * 8 + t + 2;
            if (s2 < 64) stage_slot(s2);
            if (t == 6) {
                // W2 fragments direct from L2 (512 KB matrix, XCD-resident)
                #pragma unroll
                for (int kk2 = 0; kk2 < 4; ++kk2)
                    #pragma unroll
                    for (int nt = 0; nt < 4; ++nt)
                        bfr2[kk2][nt] = *(const bf16x8*)&BT2[
                            (size_t)(wn * 64 + nt * 16 + (lane & 15)) * HIDDEN
                            + ct * 128 + kk2 * 32 + q * 8];
            }
            mfma_step((b0 + t) % 3);
        }

        // ---- GraphNorm1 + leaky + r1 + scaled xs2 tile -> sX
        #pragma unroll
        for (int nt = 0; nt < 2; ++nt) {
            int cl = wn * 32 + nt * 16 + (lane & 15);
            int colg = ct * 128 + cl;
            float lsum = 0.f;
            #pragma unroll
            for (int mt = 0; mt < 4; ++mt)
                #pragma unroll
                for (int i = 0; i < 4; ++i) lsum += acc1[mt][nt][i];
            lsum += __shfl_xor(lsum, 16);
            lsum += __shfl_xor(lsum, 32);
            float am = al1[colg] * (lsum * (1.f / 64.f));
            float gm = ga1[colg], bt = be1[colg];
            float sub[4][4], qv = 0.f;
            #pragma unroll
            for (int mt = 0; mt < 4; ++mt)
                #pragma unroll
                for (int i = 0; i < 4; ++i) {
                    float d = acc1[mt][nt][i] - am;
                    sub[mt][i] = d; qv += d * d;
                }
            qv += __shfl_xor(qv, 16);
            qv += __shfl_xor(qv, 32);
            float rs = rsqrtf(qv * (1.f / 64.f) + EPS_F);
            float rsum = 0.f;
            #pragma unroll
            for (int mt = 0; mt < 4; ++mt)
                #pragma unroll
                for (int i = 0; i < 4; ++i) {
                    float o = gm * sub[mt][i] * rs + bt;
                    o = (o >= 0.f) ? o : SLOPE_F * o;
                    rsum += o;
                    int r = wm * 64 + mt * 16 + q * 4 + i;
                    sX[r * 136 + cl] = (bf16)(o * sSo[r]);
                }
            rsum += __shfl_xor(rsum, 16);
            rsum += __shfl_xor(rsum, 32);
            if (lane < 16)
                Rb[(size_t)gw * RDIM + 512 + colg] = (bf16)(rsum * (1.f / 64.f));
        }
        // sX visibility only — keep staged global loads in flight
        asm volatile("s_waitcnt lgkmcnt(0)" ::: "memory");
        __builtin_amdgcn_s_barrier();

        // ---- GEMM2 accumulate: acc2 += xs2_tile @ W2[ct*128 : +128, 0:256]
        #pragma unroll
        for (int kk2 = 0; kk2 < 4; ++kk2) {
            bf16x8 afr[4];
            #pragma unroll
            for (int mt = 0; mt < 4; ++mt)
                afr[mt] = *(const bf16x8*)&sX[(wm * 64 + mt * 16 + (lane & 15)) * 136 + kk2 * 32 + q * 8];
            #pragma unroll
            for (int mt = 0; mt < 4; ++mt)
                #pragma unroll
                for (int nt = 0; nt < 4; ++nt)
                    acc2[mt][nt] = __builtin_amdgcn_mfma_f32_16x16x32_bf16(
                        afr[mt], bfr2[kk2][nt], acc2[mt][nt], 0, 0, 0);
        }
        // no barrier needed: sX is next written after 8 barriers of next ct's
        // K-loop, which every wave (incl. this reader) participates in first
    }

    // ---- epilogue: drain + full sync before sT overwrites staging bufs
    asm volatile("s_waitcnt vmcnt(0)" ::: "memory");
    __syncthreads();

    bf16* sT = sm;                       // [256 ch][136 pitch], wave-local quads
    #pragma unroll
    for (int nt = 0; nt < 4; ++nt) {
        int cl = wn * 64 + nt * 16 + (lane & 15);
        #pragma unroll
        for (int mt = 0; mt < 4; ++mt)
            #pragma unroll
            for (int i = 0; i < 4; ++i)
                sT[cl * 136 + wm * 64 + mt * 16 + q * 4 + i] = (bf16)acc2[mt][nt][i];
    }
    asm volatile("s_waitcnt lgkmcnt(0)" ::: "memory");   // wave-local LDS RAW

    const bf16* ag = adjb + ((size_t)gw << 12);
    floatx4 hh[4][4] = {};
    #pragma unroll
    for (int kk = 0; kk < 2; ++kk) {
        bf16x8 afr[4], bfr[4];
        #pragma unroll
        for (int mt = 0; mt < 4; ++mt)
            afr[mt] = *(const bf16x8*)&ag[(mt * 16 + (lane & 15)) * 64 + kk * 32 + q * 8];
        #pragma unroll
        for (int nt = 0; nt < 4; ++nt)
            bfr[nt] = *(const bf16x8*)&sT[(wn * 64 + nt * 16 + (lane & 15)) * 136 + wm * 64 + kk * 32 + q * 8];
        #pragma unroll
        for (int mt = 0; mt < 4; ++mt)
            #pragma unroll
            for (int nt = 0; nt < 4; ++nt)
                hh[mt][nt] = __builtin_amdgcn_mfma_f32_16x16x32_bf16(afr[mt], bfr[nt], hh[mt][nt], 0, 0, 0);
    }

    #pragma unroll
    for (int nt = 0; nt < 4; ++nt) {
        int colg = wn * 64 + nt * 16 + (lane & 15);
        float lsum = 0.f;
        #pragma unroll
        for (int mt = 0; mt < 4; ++mt)
            #pragma unroll
            for (int i = 0; i < 4; ++i) lsum += hh[mt][nt][i];
        lsum += __shfl_xor(lsum, 16);
        lsum += __shfl_xor(lsum, 32);
        float am = al2[colg] * (lsum * (1.f / 64.f));
        float gm = ga2[colg], bt = be2[colg];
        float sub[4][4], qv = 0.f;
        #pragma unroll
        for (int mt = 0; mt < 4; ++mt)
            #pragma unroll
            for (int i = 0; i < 4; ++i) {
                float d = hh[mt][nt][i] - am;
                sub[mt][i] = d; qv += d * d;
            }
        qv += __shfl_xor(qv, 16);
        qv += __shfl_xor(qv, 32);
        float rs = rsqrtf(qv * (1.f / 64.f) + EPS_F);
        float rsum = 0.f;
        #pragma unroll
        for (int mt = 0; mt < 4; ++mt)
            #pragma unroll
            for (int i = 0; i < 4; ++i) {
                float o = gm * sub[mt][i] * rs + bt;
                rsum += (o >= 0.f) ? o : SLOPE_F * o;
            }
        rsum += __shfl_xor(rsum, 16);
        rsum += __shfl_xor(rsum, 32);
        if (lane < 16)
            Rb[(size_t)gw * RDIM + 1536 + colg] = (bf16)(rsum * (1.f / 64.f));
    }
}

__device__ __forceinline__ void swizzle_block(int cb, int& bx, int& by)
{
    int b = blockIdx.y * gridDim.x + blockIdx.x;
    int xcd = b & 7, t = b >> 3;
    bx = t % cb;
    by = (t / cb) * 8 + xcd;
}

// --------------------- readout GEMM (fp32 C), T4 counted-vmcnt depth-3 loop
__global__ __launch_bounds__(256) void k_gemm_ro(
    const bf16* __restrict__ A, const bf16* __restrict__ BT,
    float* __restrict__ Cout)
{
    __shared__ __align__(16) bf16 sm[65536];   // 4 bufs x 16384 el
    const int tid = threadIdx.x;
    const int lane = tid & 63, wave = tid >> 6, q = lane >> 4;
    const int wm = wave & 1, wn = wave >> 1;
    int bx, by; swizzle_block(gridDim.x, bx, by);
    const int row0 = by * 128, col0 = bx * 128;

    floatx4 acc[4][4] = {};

    auto stage = [&](int k0, int buf) {        // 8 vm-insts per thread
        #pragma unroll
        for (int i = 0; i < 4; ++i) {
            int u = (wave * 4 + i) * 64 + lane;
            int r = u >> 3, c = (u & 7) ^ (r & 7);
            GLDS16(A  + (size_t)(row0 + r) * RDIM + (k0 + c * 8),
                   sm + buf * 16384 + (wave * 4 + i) * 512);
            GLDS16(BT + (size_t)(col0 + r) * RDIM + (k0 + c * 8),
                   sm + buf * 16384 + 8192 + (wave * 4 + i) * 512);
        }
    };
    auto step = [&](int buf) {
        const bf16* sA = sm + buf * 16384;
        const bf16* sB = sA + 8192;
        #pragma unroll
        for (int kk = 0; kk < 2; ++kk) {
            bf16x8 afr[4], bfr[4];
            int cw = kk * 4 + q;
            #pragma unroll
            for (int mt = 0; mt < 4; ++mt) {
                int r = wm * 64 + mt * 16 + (lane & 15);
                afr[mt] = *(const bf16x8*)&sA[(r * 8 + (cw ^ (r & 7))) * 8];
            }
            #pragma unroll
            for (int nt = 0; nt < 4; ++nt) {
                int r = wn * 64 + nt * 16 + (lane & 15);
                bfr[nt] = *(const bf16x8*)&sB[(r * 8 + (cw ^ (r & 7))) * 8];
            }
            #pragma unroll
            for (int mt = 0; mt < 4; ++mt)
                #pragma unroll
                for (int nt = 0; nt < 4; ++nt)
                    acc[mt][nt] = __builtin_amdgcn_mfma_f32_16x16x32_bf16(
                        afr[mt], bfr[nt], acc[mt][nt], 0, 0, 0);
        }
    };

    stage(0, 0); stage(64, 1); stage(128, 2);
    #pragma unroll 1
    for (int t = 0; t < 26; ++t) {
        asm volatile("s_waitcnt vmcnt(16)" ::: "memory");
        __builtin_amdgcn_s_barrier();
        if (t < 25) stage((t + 3) * 64, (t + 3) & 3);
        step(t & 3);
    }
    asm volatile("s_waitcnt vmcnt(8)" ::: "memory");
    __builtin_amdgcn_s_barrier();
    step(2);
    asm volatile("s_waitcnt vmcnt(0)" ::: "memory");
    __builtin_amdgcn_s_barrier();
    step(3);

    #pragma unroll
    for (int mt = 0; mt < 4; ++mt)
        #pragma unroll
        for (int nt = 0; nt < 4; ++nt) {
            int col = col0 + wn * 64 + nt * 16 + (lane & 15);
            #pragma unroll
            for (int i = 0; i < 4; ++i) {
                int row = row0 + wm * 64 + mt * 16 + q * 4 + i;
                Cout[(size_t)row * EMB_DIM + col] = acc[mt][nt][i];
            }
        }
}

// ------------------------------------------------------- InstanceNorm + leaky
__global__ __launch_bounds__(256) void k_instnorm(
    const float* __restrict__ emb, float* __restrict__ out)
{
    int row = blockIdx.x, tid = threadIdx.x;
    int lane = tid & 63, wave = tid >> 6;
    __shared__ float sS[4], sQ[4];
    float v0 = emb[(size_t)row * EMB_DIM + tid];
    float v1 = emb[(size_t)row * EMB_DIM + 256 + tid];
    float s = v0 + v1, q = v0 * v0 + v1 * v1;
    #pragma unroll
    for (int off = 32; off; off >>= 1) {
        s += __shfl_down(s, off);
        q += __shfl_down(q, off);
    }
    if (lane == 0) { sS[wave] = s; sQ[wave] = q; }
    __syncthreads();
    float S = sS[0] + sS[1] + sS[2] + sS[3];
    float Q = sQ[0] + sQ[1] + sQ[2] + sQ[3];
    float mu = S * (1.f / 512.f);
    float var = Q * (1.f / 512.f) - mu * mu;
    float rs = rsqrtf(var + EPS_F);
    float o0 = (v0 - mu) * rs; o0 = (o0 >= 0.f) ? o0 : SLOPE_F * o0;
    float o1 = (v1 - mu) * rs; o1 = (o1 >= 0.f) ? o1 : SLOPE_F * o1;
    out[(size_t)row * EMB_DIM + tid]       = o0;
    out[(size_t)row * EMB_DIM + 256 + tid] = o1;
}

// ----------------------------------------------------------------- launcher
extern "C" void kernel_launch(void* const* d_in, const int* in_sizes, int n_in,
                              void* d_out, int out_size, void* d_ws, size_t ws_size,
                              hipStream_t stream) {
    const float* x    = (const float*)d_in[0];
    const float* ew   = (const float*)d_in[1];
    const float* W1   = (const float*)d_in[2];
    const float* W2   = (const float*)d_in[3];
    const float* Wemb = (const float*)d_in[4];
    const float* a1   = (const float*)d_in[5];
    const float* g1   = (const float*)d_in[6];
    const float* b1   = (const float*)d_in[7];
    const float* a2   = (const float*)d_in[8];
    const float* g2   = (const float*)d_in[9];
    const float* b2   = (const float*)d_in[10];
    const int* esrc   = (const int*)d_in[11];
    const int* edst   = (const int*)d_in[12];
    float* out = (float*)d_out;

    char* ws = (char*)d_ws;
    const size_t MB = 1024ull * 1024ull;
    bf16*  adjb   = (bf16*)(ws);                       // 8 MB
    float* scl_o  = (float*)(ws + 8 * MB);             // 256 KB
    bf16*  Rb     = (bf16*)(ws + 9 * MB);              // 3.5 MB
    bf16*  W1T    = (bf16*)(ws + 13 * MB);             // 1 MB
    bf16*  W2T    = (bf16*)(ws + 14 * MB);             // 0.5 MB
    bf16*  WembT  = (bf16*)(ws + 15 * MB);             // 1.75 MB
    float* emb    = (float*)(ws + 17 * MB);            // 2 MB
    bf16*  axs1   = (bf16*)(ws + 20 * MB);             // 64 MB

    k_graph_build<<<N_GRAPHS, 256, 0, stream>>>(esrc, edst, ew, adjb, scl_o);
    k_transpose_t<<<dim3(IN_FEATS / 64, HIDDEN / 64), 256, 0, stream>>>(W1, W1T, IN_FEATS, HIDDEN);
    k_transpose_t<<<dim3(HIDDEN / 64, H4 / 64), 256, 0, stream>>>(W2, W2T, HIDDEN, H4);
    k_transpose_t<<<dim3(RDIM / 64, EMB_DIM / 64), 256, 0, stream>>>(Wemb, WembT, RDIM, EMB_DIM);

    k_prep_agg1<<<N_GRAPHS * 2, 256, 0, stream>>>(x, scl_o, adjb, axs1, Rb);

    k_gemm12<<<N_NODES / 128, 512, 0, stream>>>(
        axs1, W1T, W2T, adjb, a1, g1, b1, a2, g2, b2, scl_o, Rb);

    k_gemm_ro<<<dim3(EMB_DIM / 128, N_GRAPHS / 128), 256, 0, stream>>>(
        Rb, WembT, emb);
    k_instnorm<<<N_GRAPHS, 256, 0, stream>>>(emb, out);

    (void)in_sizes; (void)n_in; (void)out_size; (void)ws_size;
}

// Round 8
// 422.027 us; speedup vs baseline: 1.2253x; 1.2253x over previous
//
#include <hip/hip_runtime.h>
#include <hip/hip_bf16.h>
#include <stdint.h>

#define N_NODES   65536
#define N_GRAPHS  1024
#define N_EDGES   1048576
#define IN_FEATS  512
#define HIDDEN    1024
#define H4        256
#define EMB_DIM   512
#define RDIM      1792   // 512 + 1024 + 256
#define EPS_F     1e-5f
#define SLOPE_F   0.01f

typedef __bf16 bf16;
typedef __bf16 bf16x4 __attribute__((ext_vector_type(4)));
typedef __bf16 bf16x8 __attribute__((ext_vector_type(8)));
typedef float  floatx4 __attribute__((ext_vector_type(4)));

#define GLDS16(gp, lp) __builtin_amdgcn_global_load_lds( \
    (const __attribute__((address_space(1))) void*)(gp), \
    (__attribute__((address_space(3))) void*)(lp), 16, 0, 0)

// -------------------------------------------- fused edge pass, per graph
__global__ __launch_bounds__(256) void k_graph_build(
    const int* __restrict__ src, const int* __restrict__ dst,
    const float* __restrict__ ew,
    bf16* __restrict__ adjb, float* __restrict__ scl_o)
{
    __shared__ float sAdj[4096];
    __shared__ float sDegO[64], sDegI[64];
    int g = blockIdx.x, tid = threadIdx.x;
    for (int i = tid; i < 4096; i += 256) sAdj[i] = 0.f;
    if (tid < 64) { sDegO[tid] = 0.f; sDegI[tid] = 0.f; }
    __syncthreads();
    int e0 = g * 1024;
    #pragma unroll
    for (int i = 0; i < 4; ++i) {
        int e = e0 + i * 256 + tid;
        int s = src[e] & 63, d = dst[e] & 63;
        atomicAdd(&sAdj[(d << 6) | s], ew[e]);
        atomicAdd(&sDegO[s], 1.f);
        atomicAdd(&sDegI[d], 1.f);
    }
    __syncthreads();
    if (tid < 64) scl_o[g * 64 + tid] = rsqrtf(fmaxf(sDegO[tid], 1.f));
    bf16* ag = adjb + ((size_t)g << 12);
    for (int i = tid; i < 4096; i += 256) {
        float si = rsqrtf(fmaxf(sDegI[i >> 6], 1.f));
        ag[i] = (bf16)(sAdj[i] * si);
    }
}

// ---------------- tiled transpose W[K][N] -> WT[N][K] bf16 (coalesced r/w)
__global__ __launch_bounds__(256) void k_transpose_t(
    const float* __restrict__ W, bf16* __restrict__ WT, int K, int N)
{
    __shared__ float sT[64][65];            // pitch 65: conflict-free cols
    const int k0 = blockIdx.x * 64, n0 = blockIdx.y * 64;
    const int tid = threadIdx.x;
    const int lr = tid >> 4, lc = (tid & 15) * 4;
    #pragma unroll
    for (int i = 0; i < 4; ++i) {
        int row = lr + i * 16;
        float4 v = *(const float4*)&W[(size_t)(k0 + row) * N + n0 + lc];
        sT[row][lc + 0] = v.x; sT[row][lc + 1] = v.y;
        sT[row][lc + 2] = v.z; sT[row][lc + 3] = v.w;
    }
    __syncthreads();
    const int nn = tid >> 2, kk0 = (tid & 3) * 16;
    #pragma unroll
    for (int h = 0; h < 2; ++h) {
        bf16x8 o;
        #pragma unroll
        for (int j = 0; j < 8; ++j)
            o[j] = (bf16)sT[kk0 + h * 8 + j][nn];
        *(bf16x8*)&WT[(size_t)(n0 + nn) * K + k0 + kk0 + h * 8] = o;
    }
}

// -------------------------------------- fused prep + agg layer 1 (2 blk/graph)
// v3: one column per thread; coalesced b32 global reads; free r0; XOR-swizzled
// transposed LDS tile; MFMA B-fragment = single conflict-free ds_read_b128.
__global__ __launch_bounds__(256) void k_prep_agg1(
    const float* __restrict__ x, const float* __restrict__ so,
    const bf16* __restrict__ adjb,
    bf16* __restrict__ axs1, bf16* __restrict__ Rb)
{
    __shared__ __align__(16) bf16 sXrT[256 * 64];  // xs^T [col][64], swizzled
    __shared__ __align__(16) bf16 sOut[64 * 264];
    __shared__ float sSo[64];
    int g = blockIdx.x >> 1, half = blockIdx.x & 1;
    int tid = threadIdx.x, lane = tid & 63, wave = tid >> 6, q = lane >> 4;
    if (tid < 64) sSo[tid] = so[g * 64 + tid];

    const float* xg = x + (size_t)g * 64 * IN_FEATS + half * 256;
    const bf16* ag = adjb + ((size_t)g << 12);

    bf16x8 af[4][2];
    #pragma unroll
    for (int mt = 0; mt < 4; ++mt)
        #pragma unroll
        for (int kk = 0; kk < 2; ++kk)
            af[mt][kk] = *(const bf16x8*)&ag[(mt * 16 + (lane & 15)) * 64 + kk * 32 + q * 8];
    __syncthreads();                       // sSo visible

    float r0 = 0.f;
    const int sw = tid & 7;
    #pragma unroll
    for (int r8 = 0; r8 < 8; ++r8) {
        bf16x8 p;
        #pragma unroll
        for (int j = 0; j < 8; ++j) {
            int r = r8 * 8 + j;
            float v = xg[(size_t)r * IN_FEATS + tid];
            r0 += v;
            p[j] = (bf16)(v * sSo[r]);
        }
        *(bf16x8*)&sXrT[tid * 64 + ((r8 ^ sw) * 8)] = p;
    }
    Rb[(size_t)g * RDIM + half * 256 + tid] = (bf16)(r0 * (1.f / 64.f));
    __syncthreads();

    #pragma unroll
    for (int nt = 0; nt < 4; ++nt) {
        int cl = wave * 64 + nt * 16 + (lane & 15);     // 0..255
        floatx4 acc[4] = {};
        #pragma unroll
        for (int kk = 0; kk < 2; ++kk) {
            bf16x8 bfrag = *(const bf16x8*)&sXrT[cl * 64 + (((kk * 4 + q) ^ (cl & 7)) * 8)];
            #pragma unroll
            for (int mt = 0; mt < 4; ++mt)
                acc[mt] = __builtin_amdgcn_mfma_f32_16x16x32_bf16(af[mt][kk], bfrag, acc[mt], 0, 0, 0);
        }
        #pragma unroll
        for (int mt = 0; mt < 4; ++mt)
            #pragma unroll
            for (int i = 0; i < 4; ++i)
                sOut[(mt * 16 + q * 4 + i) * 264 + cl] = (bf16)acc[mt][i];
    }
    __syncthreads();
    #pragma unroll
    for (int it = 0; it < 8; ++it) {
        int idx = it * 256 + tid;
        int d = idx >> 5, c8 = idx & 31;
        *(bf16x8*)&axs1[(size_t)(g * 64 + d) * IN_FEATS + half * 256 + c8 * 8] =
            *(const bf16x8*)&sOut[d * 264 + c8 * 8];
    }
}

// ============================ fused GEMM1 + GN1 + GEMM2 + agg + GN2 ==========
// (round-6 verified version: 3-buf counted-vmcnt, W2 staged to LDS; ~154 us)
__global__ __launch_bounds__(512) void k_gemm12(
    const bf16* __restrict__ A, const bf16* __restrict__ BT1,
    const bf16* __restrict__ BT2, const bf16* __restrict__ adjb,
    const float* __restrict__ al1, const float* __restrict__ ga1, const float* __restrict__ be1,
    const float* __restrict__ al2, const float* __restrict__ ga2, const float* __restrict__ be2,
    const float* __restrict__ so, bf16* __restrict__ Rb)
{
    __shared__ __align__(16) bf16 sm[66560];
    __shared__ float sSo[128];
    const int tid = threadIdx.x;
    const int lane = tid & 63, wave = tid >> 6, q = lane >> 4;
    const int wm = wave >> 2, wn = wave & 3;
    const int by = blockIdx.x;
    const int row0 = by * 128;
    const int gw = by * 2 + wm;
    if (tid < 128) sSo[tid] = so[row0 + tid];

    floatx4 acc2[4][4] = {};
    bf16* sX = sm + 49152;

    #pragma unroll 1
    for (int ct = 0; ct < 8; ++ct) {
        floatx4 acc1[4][2] = {};

        auto stage_ab = [&](int k0, int buf) {       // 4 vm-insts per wave
            #pragma unroll
            for (int ro = 0; ro < 2; ++ro) {
                int u = ro * 4096 + wave * 512 + lane * 8;
                int r = u >> 6, c = ((u >> 3) & 7) ^ (r & 7);
                GLDS16(A   + (size_t)(row0 + r) * IN_FEATS + k0 + c * 8,
                       sm + buf * 16384 + ro * 4096 + wave * 512);
                GLDS16(BT1 + (size_t)(ct * 128 + r) * IN_FEATS + k0 + c * 8,
                       sm + buf * 16384 + 8192 + ro * 4096 + wave * 512);
            }
        };
        auto stage_w2 = [&](int h, int buf) {        // 4 vm-insts per wave
            #pragma unroll
            for (int ro = 0; ro < 4; ++ro) {
                int u = ro * 4096 + wave * 512 + lane * 8;
                int r = u >> 6, c = ((u >> 3) & 7) ^ (r & 7);
                GLDS16(BT2 + (size_t)r * HIDDEN + ct * 128 + h * 64 + c * 8,
                       sm + buf * 16384 + ro * 4096 + wave * 512);
            }
        };
        auto mfma_step = [&](int buf) {
            const bf16* sA = sm + buf * 16384;
            const bf16* sB = sA + 8192;
            #pragma unroll
            for (int kk = 0; kk < 2; ++kk) {
                bf16x8 afr[4], bfr[2];
                int cw = kk * 4 + q;
                #pragma unroll
                for (int mt = 0; mt < 4; ++mt) {
                    int r = wm * 64 + mt * 16 + (lane & 15);
                    afr[mt] = *(const bf16x8*)&sA[(r * 8 + (cw ^ (r & 7))) * 8];
                }
                #pragma unroll
                for (int nt = 0; nt < 2; ++nt) {
                    int r = wn * 32 + nt * 16 + (lane & 15);
                    bfr[nt] = *(const bf16x8*)&sB[(r * 8 + (cw ^ (r & 7))) * 8];
                }
                #pragma unroll
                for (int mt = 0; mt < 4; ++mt)
                    #pragma unroll
                    for (int nt = 0; nt < 2; ++nt)
                        acc1[mt][nt] = __builtin_amdgcn_mfma_f32_16x16x32_bf16(
                            afr[mt], bfr[nt], acc1[mt][nt], 0, 0, 0);
            }
        };

        stage_ab(0, 0);
        stage_ab(64, 1);

        #pragma unroll
        for (int t = 0; t < 8; ++t) {
            asm volatile("s_waitcnt vmcnt(4)" ::: "memory");
            __builtin_amdgcn_s_barrier();
            if (t < 6)       stage_ab((t + 2) * 64, (t + 2) % 3);
            else if (t == 6) stage_w2(0, 2);
            else             stage_w2(1, 0);
            mfma_step(t % 3);
        }

        #pragma unroll
        for (int nt = 0; nt < 2; ++nt) {
            int cl = wn * 32 + nt * 16 + (lane & 15);
            int colg = ct * 128 + cl;
            float lsum = 0.f;
            #pragma unroll
            for (int mt = 0; mt < 4; ++mt)
                #pragma unroll
                for (int i = 0; i < 4; ++i) lsum += acc1[mt][nt][i];
            lsum += __shfl_xor(lsum, 16);
            lsum += __shfl_xor(lsum, 32);
            float am = al1[colg] * (lsum * (1.f / 64.f));
            float gm = ga1[colg], bt = be1[colg];
            float sub[4][4], qv = 0.f;
            #pragma unroll
            for (int mt = 0; mt < 4; ++mt)
                #pragma unroll
                for (int i = 0; i < 4; ++i) {
                    float d = acc1[mt][nt][i] - am;
                    sub[mt][i] = d; qv += d * d;
                }
            qv += __shfl_xor(qv, 16);
            qv += __shfl_xor(qv, 32);
            float rs = rsqrtf(qv * (1.f / 64.f) + EPS_F);
            float rsum = 0.f;
            #pragma unroll
            for (int mt = 0; mt < 4; ++mt)
                #pragma unroll
                for (int i = 0; i < 4; ++i) {
                    float o = gm * sub[mt][i] * rs + bt;
                    o = (o >= 0.f) ? o : SLOPE_F * o;
                    rsum += o;
                    int r = wm * 64 + mt * 16 + q * 4 + i;
                    sX[r * 136 + cl] = (bf16)(o * sSo[r]);
                }
            rsum += __shfl_xor(rsum, 16);
            rsum += __shfl_xor(rsum, 32);
            if (lane < 16)
                Rb[(size_t)gw * RDIM + 512 + colg] = (bf16)(rsum * (1.f / 64.f));
        }
        asm volatile("s_waitcnt vmcnt(0)" ::: "memory");   // W2 halves landed
        __syncthreads();                                   // sX + W2 visible

        #pragma unroll
        for (int kk2 = 0; kk2 < 4; ++kk2) {
            const bf16* sW = sm + ((kk2 < 2) ? 2 : 0) * 16384;
            int cw = (kk2 & 1) * 4 + q;
            bf16x8 afr[4], bfr[4];
            #pragma unroll
            for (int mt = 0; mt < 4; ++mt)
                afr[mt] = *(const bf16x8*)&sX[(wm * 64 + mt * 16 + (lane & 15)) * 136 + kk2 * 32 + q * 8];
            #pragma unroll
            for (int nt = 0; nt < 4; ++nt) {
                int r = wn * 64 + nt * 16 + (lane & 15);
                bfr[nt] = *(const bf16x8*)&sW[(r * 8 + (cw ^ (r & 7))) * 8];
            }
            #pragma unroll
            for (int mt = 0; mt < 4; ++mt)
                #pragma unroll
                for (int nt = 0; nt < 4; ++nt)
                    acc2[mt][nt] = __builtin_amdgcn_mfma_f32_16x16x32_bf16(
                        afr[mt], bfr[nt], acc2[mt][nt], 0, 0, 0);
        }
        __syncthreads();                 // protect W2 bufs/sX before restage
    }

    bf16* sT = sm;                       // [256 ch][136 pitch], wave-local quads
    #pragma unroll
    for (int nt = 0; nt < 4; ++nt) {
        int cl = wn * 64 + nt * 16 + (lane & 15);
        #pragma unroll
        for (int mt = 0; mt < 4; ++mt)
            #pragma unroll
            for (int i = 0; i < 4; ++i)
                sT[cl * 136 + wm * 64 + mt * 16 + q * 4 + i] = (bf16)acc2[mt][nt][i];
    }
    asm volatile("s_waitcnt lgkmcnt(0)" ::: "memory");   // wave-local LDS RAW

    const bf16* ag = adjb + ((size_t)gw << 12);
    floatx4 hh[4][4] = {};
    #pragma unroll
    for (int kk = 0; kk < 2; ++kk) {
        bf16x8 afr[4], bfr[4];
        #pragma unroll
        for (int mt = 0; mt < 4; ++mt)
            afr[mt] = *(const bf16x8*)&ag[(mt * 16 + (lane & 15)) * 64 + kk * 32 + q * 8];
        #pragma unroll
        for (int nt = 0; nt < 4; ++nt)
            bfr[nt] = *(const bf16x8*)&sT[(wn * 64 + nt * 16 + (lane & 15)) * 136 + wm * 64 + kk * 32 + q * 8];
        #pragma unroll
        for (int mt = 0; mt < 4; ++mt)
            #pragma unroll
            for (int nt = 0; nt < 4; ++nt)
                hh[mt][nt] = __builtin_amdgcn_mfma_f32_16x16x32_bf16(afr[mt], bfr[nt], hh[mt][nt], 0, 0, 0);
    }

    #pragma unroll
    for (int nt = 0; nt < 4; ++nt) {
        int colg = wn * 64 + nt * 16 + (lane & 15);
        float lsum = 0.f;
        #pragma unroll
        for (int mt = 0; mt < 4; ++mt)
            #pragma unroll
            for (int i = 0; i < 4; ++i) lsum += hh[mt][nt][i];
        lsum += __shfl_xor(lsum, 16);
        lsum += __shfl_xor(lsum, 32);
        float am = al2[colg] * (lsum * (1.f / 64.f));
        float gm = ga2[colg], bt = be2[colg];
        float sub[4][4], qv = 0.f;
        #pragma unroll
        for (int mt = 0; mt < 4; ++mt)
            #pragma unroll
            for (int i = 0; i < 4; ++i) {
                float d = hh[mt][nt][i] - am;
                sub[mt][i] = d; qv += d * d;
            }
        qv += __shfl_xor(qv, 16);
        qv += __shfl_xor(qv, 32);
        float rs = rsqrtf(qv * (1.f / 64.f) + EPS_F);
        float rsum = 0.f;
        #pragma unroll
        for (int mt = 0; mt < 4; ++mt)
            #pragma unroll
            for (int i = 0; i < 4; ++i) {
                float o = gm * sub[mt][i] * rs + bt;
                rsum += (o >= 0.f) ? o : SLOPE_F * o;
            }
        rsum += __shfl_xor(rsum, 16);
        rsum += __shfl_xor(rsum, 32);
        if (lane < 16)
            Rb[(size_t)gw * RDIM + 1536 + colg] = (bf16)(rsum * (1.f / 64.f));
    }
}

__device__ __forceinline__ void swizzle_block(int cb, int& bx, int& by)
{
    int b = blockIdx.y * gridDim.x + blockIdx.x;
    int xcd = b & 7, t = b >> 3;
    bx = t % cb;
    by = (t / cb) * 8 + xcd;
}

// --------------------- readout GEMM (fp32 C), T4 counted-vmcnt depth-3 loop
__global__ __launch_bounds__(256) void k_gemm_ro(
    const bf16* __restrict__ A, const bf16* __restrict__ BT,
    float* __restrict__ Cout)
{
    __shared__ __align__(16) bf16 sm[65536];   // 4 bufs x 16384 el
    const int tid = threadIdx.x;
    const int lane = tid & 63, wave = tid >> 6, q = lane >> 4;
    const int wm = wave & 1, wn = wave >> 1;
    int bx, by; swizzle_block(gridDim.x, bx, by);
    const int row0 = by * 128, col0 = bx * 128;

    floatx4 acc[4][4] = {};

    auto stage = [&](int k0, int buf) {
        #pragma unroll
        for (int i = 0; i < 4; ++i) {
            int u = (wave * 4 + i) * 64 + lane;
            int r = u >> 3, c = (u & 7) ^ (r & 7);
            GLDS16(A  + (size_t)(row0 + r) * RDIM + (k0 + c * 8),
                   sm + buf * 16384 + (wave * 4 + i) * 512);
            GLDS16(BT + (size_t)(col0 + r) * RDIM + (k0 + c * 8),
                   sm + buf * 16384 + 8192 + (wave * 4 + i) * 512);
        }
    };
    auto step = [&](int buf) {
        const bf16* sA = sm + buf * 16384;
        const bf16* sB = sA + 8192;
        #pragma unroll
        for (int kk = 0; kk < 2; ++kk) {
            bf16x8 afr[4], bfr[4];
            int cw = kk * 4 + q;
            #pragma unroll
            for (int mt = 0; mt < 4; ++mt) {
                int r = wm * 64 + mt * 16 + (lane & 15);
                afr[mt] = *(const bf16x8*)&sA[(r * 8 + (cw ^ (r & 7))) * 8];
            }
            #pragma unroll
            for (int nt = 0; nt < 4; ++nt) {
                int r = wn * 64 + nt * 16 + (lane & 15);
                bfr[nt] = *(const bf16x8*)&sB[(r * 8 + (cw ^ (r & 7))) * 8];
            }
            #pragma unroll
            for (int mt = 0; mt < 4; ++mt)
                #pragma unroll
                for (int nt = 0; nt < 4; ++nt)
                    acc[mt][nt] = __builtin_amdgcn_mfma_f32_16x16x32_bf16(
                        afr[mt], bfr[nt], acc[mt][nt], 0, 0, 0);
        }
    };

    stage(0, 0); stage(64, 1); stage(128, 2);
    #pragma unroll 1
    for (int t = 0; t < 26; ++t) {
        asm volatile("s_waitcnt vmcnt(16)" ::: "memory");
        __builtin_amdgcn_s_barrier();
        if (t < 25) stage((t + 3) * 64, (t + 3) & 3);
        step(t & 3);
    }
    asm volatile("s_waitcnt vmcnt(8)" ::: "memory");
    __builtin_amdgcn_s_barrier();
    step(2);
    asm volatile("s_waitcnt vmcnt(0)" ::: "memory");
    __builtin_amdgcn_s_barrier();
    step(3);

    #pragma unroll
    for (int mt = 0; mt < 4; ++mt)
        #pragma unroll
        for (int nt = 0; nt < 4; ++nt) {
            int col = col0 + wn * 64 + nt * 16 + (lane & 15);
            #pragma unroll
            for (int i = 0; i < 4; ++i) {
                int row = row0 + wm * 64 + mt * 16 + q * 4 + i;
                Cout[(size_t)row * EMB_DIM + col] = acc[mt][nt][i];
            }
        }
}

// ------------------------------------------------------- InstanceNorm + leaky
__global__ __launch_bounds__(256) void k_instnorm(
    const float* __restrict__ emb, float* __restrict__ out)
{
    int row = blockIdx.x, tid = threadIdx.x;
    int lane = tid & 63, wave = tid >> 6;
    __shared__ float sS[4], sQ[4];
    float v0 = emb[(size_t)row * EMB_DIM + tid];
    float v1 = emb[(size_t)row * EMB_DIM + 256 + tid];
    float s = v0 + v1, q = v0 * v0 + v1 * v1;
    #pragma unroll
    for (int off = 32; off; off >>= 1) {
        s += __shfl_down(s, off);
        q += __shfl_down(q, off);
    }
    if (lane == 0) { sS[wave] = s; sQ[wave] = q; }
    __syncthreads();
    float S = sS[0] + sS[1] + sS[2] + sS[3];
    float Q = sQ[0] + sQ[1] + sQ[2] + sQ[3];
    float mu = S * (1.f / 512.f);
    float var = Q * (1.f / 512.f) - mu * mu;
    float rs = rsqrtf(var + EPS_F);
    float o0 = (v0 - mu) * rs; o0 = (o0 >= 0.f) ? o0 : SLOPE_F * o0;
    float o1 = (v1 - mu) * rs; o1 = (o1 >= 0.f) ? o1 : SLOPE_F * o1;
    out[(size_t)row * EMB_DIM + tid]       = o0;
    out[(size_t)row * EMB_DIM + 256 + tid] = o1;
}

// ----------------------------------------------------------------- launcher
extern "C" void kernel_launch(void* const* d_in, const int* in_sizes, int n_in,
                              void* d_out, int out_size, void* d_ws, size_t ws_size,
                              hipStream_t stream) {
    const float* x    = (const float*)d_in[0];
    const float* ew   = (const float*)d_in[1];
    const float* W1   = (const float*)d_in[2];
    const float* W2   = (const float*)d_in[3];
    const float* Wemb = (const float*)d_in[4];
    const float* a1   = (const float*)d_in[5];
    const float* g1   = (const float*)d_in[6];
    const float* b1   = (const float*)d_in[7];
    const float* a2   = (const float*)d_in[8];
    const float* g2   = (const float*)d_in[9];
    const float* b2   = (const float*)d_in[10];
    const int* esrc   = (const int*)d_in[11];
    const int* edst   = (const int*)d_in[12];
    float* out = (float*)d_out;

    char* ws = (char*)d_ws;
    const size_t MB = 1024ull * 1024ull;
    bf16*  adjb   = (bf16*)(ws);                       // 8 MB
    float* scl_o  = (float*)(ws + 8 * MB);             // 256 KB
    bf16*  Rb     = (bf16*)(ws + 9 * MB);              // 3.5 MB
    bf16*  W1T    = (bf16*)(ws + 13 * MB);             // 1 MB
    bf16*  W2T    = (bf16*)(ws + 14 * MB);             // 0.5 MB
    bf16*  WembT  = (bf16*)(ws + 15 * MB);             // 1.75 MB
    float* emb    = (float*)(ws + 17 * MB);            // 2 MB
    bf16*  axs1   = (bf16*)(ws + 20 * MB);             // 64 MB

    k_graph_build<<<N_GRAPHS, 256, 0, stream>>>(esrc, edst, ew, adjb, scl_o);
    k_transpose_t<<<dim3(IN_FEATS / 64, HIDDEN / 64), 256, 0, stream>>>(W1, W1T, IN_FEATS, HIDDEN);
    k_transpose_t<<<dim3(HIDDEN / 64, H4 / 64), 256, 0, stream>>>(W2, W2T, HIDDEN, H4);
    k_transpose_t<<<dim3(RDIM / 64, EMB_DIM / 64), 256, 0, stream>>>(Wemb, WembT, RDIM, EMB_DIM);

    k_prep_agg1<<<N_GRAPHS * 2, 256, 0, stream>>>(x, scl_o, adjb, axs1, Rb);

    k_gemm12<<<N_NODES / 128, 512, 0, stream>>>(
        axs1, W1T, W2T, adjb, a1, g1, b1, a2, g2, b2, scl_o, Rb);

    k_gemm_ro<<<dim3(EMB_DIM / 128, N_GRAPHS / 128), 256, 0, stream>>>(
        Rb, WembT, emb);
    k_instnorm<<<N_GRAPHS, 256, 0, stream>>>(emb, out);

    (void)in_sizes; (void)n_in; (void)out_size; (void)ws_size;
}